// Round 1
// baseline (255.927 us; speedup 1.0000x reference)
//
#include <hip/hip_runtime.h>
#include <stdint.h>

// Problem constants
#define BATCH   8
#define NMASK_  1024
#define SEQ     1025          // NMASK + 1 (CLS prepended)
#define NPAD    1056          // SEQ padded to multiple of 32
#define DIM     768
#define HEADS   12
#define HD      64
#define BHN     (BATCH*HEADS) // 96
#define MROWS   (BATCH*SEQ)   // 8200
#define K3      (3*DIM)       // 2304

typedef unsigned short u16;
typedef __attribute__((ext_vector_type(8))) short s8v;   // 8 bf16 (A/B frag)
typedef __attribute__((ext_vector_type(4))) float f4v;   // C/D frag
typedef __attribute__((ext_vector_type(4))) unsigned short u16x4;

__device__ __forceinline__ u16 rne_bf16(float f) {
  unsigned u = __float_as_uint(f);
  u += 0x7fffu + ((u >> 16) & 1u);      // round-to-nearest-even
  return (u16)(u >> 16);
}
__device__ __forceinline__ float bf2f(u16 u) {
  return __uint_as_float(((unsigned)u) << 16);
}

// ---------------- lengths: Lp1[b] = popcount(mask row) + 1 (CLS) -------------
__global__ __launch_bounds__(256) void k_len(const int* __restrict__ mask,
                                             int* __restrict__ lens) {
  int b = blockIdx.x, t = threadIdx.x;
  int s = 0;
  for (int j = t; j < NMASK_; j += 256) s += (mask[b * NMASK_ + j] != 0) ? 1 : 0;
  __shared__ int red[256];
  red[t] = s; __syncthreads();
  for (int st = 128; st > 0; st >>= 1) { if (t < st) red[t] += red[t + st]; __syncthreads(); }
  if (t == 0) lens[b] = red[0] + 1;
}

// ---------------- x -> bf16 ---------------------------------------------------
__global__ __launch_bounds__(256) void k_cvt_x(const float* __restrict__ x,
                                               u16* __restrict__ xb, int n4) {
  int i = blockIdx.x * 256 + threadIdx.x;
  if (i >= n4) return;
  float4 v = ((const float4*)x)[i];
  u16x4 o;
  o[0] = rne_bf16(v.x); o[1] = rne_bf16(v.y); o[2] = rne_bf16(v.z); o[3] = rne_bf16(v.w);
  *(u16x4*)&xb[i * 4] = o;
}

// ---------------- transpose+convert weights: wT[c][k] = bf16(w[k][c]) --------
__global__ __launch_bounds__(256) void k_wT(const float* __restrict__ w,
                                            u16* __restrict__ wT, int R, int C) {
  __shared__ float tile[32][33];
  int c0 = blockIdx.x * 32, r0 = blockIdx.y * 32;
  int tx = threadIdx.x & 31, ty = threadIdx.x >> 5;   // 32 x 8
  #pragma unroll
  for (int i = 0; i < 32; i += 8) tile[ty + i][tx] = w[(size_t)(r0 + ty + i) * C + c0 + tx];
  __syncthreads();
  #pragma unroll
  for (int i = 0; i < 32; i += 8)
    wT[(size_t)(c0 + ty + i) * R + r0 + tx] = rne_bf16(tile[tx][ty + i]);
}

// ---------------- zero VT pad columns (j in [SEQ, NPAD)) ---------------------
__global__ __launch_bounds__(256) void k_zpad(u16* __restrict__ VT) {
  int idx = blockIdx.x * 256 + threadIdx.x;
  const int PADW = NPAD - SEQ; // 31
  if (idx >= BHN * HD * PADW) return;
  int c = idx % PADW, rd = idx / PADW; // rd = bh*HD + d
  VT[(size_t)rd * NPAD + SEQ + c] = 0;
}

// ---------------- shared 128x128 MFMA mainloop (BK=32, reg-staged LDS) -------
// A: [M][768] bf16 row-major, Bt: [Ncols][768] bf16 (k contiguous)
__device__ __forceinline__ void gemm_mainloop(const u16* __restrict__ A,
                                              const u16* __restrict__ Bt,
                                              int M, int m0, int n0,
                                              f4v acc[4][4]) {
  __shared__ alignas(16) u16 lA[128 * 40];  // stride 40 u16 = 80B (bank spread)
  __shared__ alignas(16) u16 lB[128 * 40];
  const int t = threadIdx.x;
  const int w = t >> 6, l = t & 63, lg = l >> 4, lr = l & 15;
  const int wr = w >> 1, wc = w & 1;
  #pragma unroll
  for (int fm = 0; fm < 4; fm++)
    #pragma unroll
    for (int fn = 0; fn < 4; fn++) { f4v z = {0.f, 0.f, 0.f, 0.f}; acc[fm][fn] = z; }

  for (int k0 = 0; k0 < DIM; k0 += 32) {
    __syncthreads();
    #pragma unroll
    for (int p = 0; p < 2; p++) {                 // 512 chunks of 8 bf16 per tile
      int c = p * 256 + t;
      int row = c >> 2, seg = c & 3;
      int gr = m0 + row; gr = gr < M ? gr : M - 1; // clamp M edge
      *(s8v*)&lA[row * 40 + seg * 8] = *(const s8v*)&A[(size_t)gr * DIM + k0 + seg * 8];
      *(s8v*)&lB[row * 40 + seg * 8] = *(const s8v*)&Bt[(size_t)(n0 + row) * DIM + k0 + seg * 8];
    }
    __syncthreads();
    s8v a[4], bb[4];
    #pragma unroll
    for (int fm = 0; fm < 4; fm++) a[fm] = *(const s8v*)&lA[(wr * 64 + fm * 16 + lr) * 40 + lg * 8];
    #pragma unroll
    for (int fn = 0; fn < 4; fn++) bb[fn] = *(const s8v*)&lB[(wc * 64 + fn * 16 + lr) * 40 + lg * 8];
    #pragma unroll
    for (int fm = 0; fm < 4; fm++)
      #pragma unroll
      for (int fn = 0; fn < 4; fn++)
        acc[fm][fn] = __builtin_amdgcn_mfma_f32_16x16x32_bf16(a[fm], bb[fn], acc[fm][fn], 0, 0, 0);
  }
}

// ---------------- QKV GEMM: scatter into Q (x0.125), K, V^T ------------------
__global__ __launch_bounds__(256) void k_gemm_qkv(const u16* __restrict__ xb,
                                                  const u16* __restrict__ wqkvT,
                                                  const float* __restrict__ bqkv,
                                                  u16* __restrict__ Q,
                                                  u16* __restrict__ Kb,
                                                  u16* __restrict__ VT) {
  int m0 = blockIdx.x * 128, n0 = blockIdx.y * 128;
  f4v acc[4][4];
  gemm_mainloop(xb, wqkvT, MROWS, m0, n0, acc);
  const int t = threadIdx.x;
  const int w = t >> 6, l = t & 63, lg = l >> 4, lr = l & 15;
  const int wr = w >> 1, wc = w & 1;
  #pragma unroll
  for (int fn = 0; fn < 4; fn++) {
    int gc = n0 + wc * 64 + fn * 16 + lr;          // 0..2303
    int which = gc / DIM;                          // 0=q 1=k 2=v
    int rem = gc - which * DIM;
    int h = rem >> 6, d = rem & 63;
    float bias = bqkv[gc];
    #pragma unroll
    for (int fm = 0; fm < 4; fm++) {
      #pragma unroll
      for (int r = 0; r < 4; r++) {
        int gm = m0 + wr * 64 + fm * 16 + lg * 4 + r;
        if (gm >= MROWS) continue;
        int b = gm / SEQ, n = gm - b * SEQ;
        int bh = b * HEADS + h;
        float v = acc[fm][fn][r] + bias;
        if (which == 0)      Q [(size_t)(bh * NPAD + n) * HD + d] = rne_bf16(v * 0.125f);
        else if (which == 1) Kb[(size_t)(bh * NPAD + n) * HD + d] = rne_bf16(v);
        else                 VT[(size_t)(bh * HD + d) * NPAD + n] = rne_bf16(v);
      }
    }
  }
}

// ---------------- per-(b,h) mean of V over all SEQ rows ----------------------
__global__ __launch_bounds__(256) void k_vmean(const u16* __restrict__ VT,
                                               float* __restrict__ vmean) {
  int bh = blockIdx.x, t = threadIdx.x;
  int d = t >> 2, part = t & 3;
  const u16* row = VT + (size_t)(bh * HD + d) * NPAD;
  float s = 0.f;
  for (int jc = part * 264; jc < part * 264 + 264; jc += 8) {
    if (jc + 8 <= SEQ) {
      s8v v = *(const s8v*)&row[jc];
      #pragma unroll
      for (int e = 0; e < 8; e++) s += bf2f((u16)v[e]);
    } else {
      for (int e = 0; e < 8; e++) if (jc + e < SEQ) s += bf2f(row[jc + e]);
    }
  }
  __shared__ float red[256];
  red[t] = s; __syncthreads();
  if (part == 0)
    vmean[bh * HD + d] = (red[t] + red[t + 1] + red[t + 2] + red[t + 3]) * (1.0f / (float)SEQ);
}

// ---------------- flash attention over the valid prefix ----------------------
// grid (17, 96); 4 waves x 16 Q-rows. Q pre-scaled by 0.125.
__global__ __launch_bounds__(256) void k_attn(const u16* __restrict__ Q,
                                              const u16* __restrict__ Kb,
                                              const u16* __restrict__ VT,
                                              const int* __restrict__ lens,
                                              u16* __restrict__ aout) {
  int bh = blockIdx.y; int b = bh / HEADS, h = bh - b * HEADS;
  int Lp1 = lens[b];
  int q0 = blockIdx.x * 64;
  if (q0 >= Lp1) return;                      // rows handled by k_fill
  __shared__ alignas(16) u16 Kt[32 * 64];     // [j][d], XOR-swizzled 16B granules
  __shared__ alignas(16) u16 Vt[64 * 32];     // [d][j], XOR-swizzled
  __shared__ alignas(16) u16 Pt[4][16 * 40];  // per-wave P tile, 80B stride
  const int t = threadIdx.x, w = t >> 6, l = t & 63, lg = l >> 4, lr = l & 15;
  const u16* Qbh = Q  + (size_t)bh * NPAD * HD;
  const u16* Kbh = Kb + (size_t)bh * NPAD * HD;
  const u16* Vbh = VT + (size_t)bh * HD * NPAD;

  int qi = q0 + w * 16 + lr;                  // A-frag row (l&15)
  s8v qf[2];
  qf[0] = *(const s8v*)&Qbh[(size_t)qi * HD +      lg * 8];
  qf[1] = *(const s8v*)&Qbh[(size_t)qi * HD + 32 + lg * 8];

  f4v o[4];
  #pragma unroll
  for (int fd = 0; fd < 4; fd++) { f4v z = {0.f, 0.f, 0.f, 0.f}; o[fd] = z; }
  float mrow[4], ssum[4];
  #pragma unroll
  for (int r = 0; r < 4; r++) { mrow[r] = -1e30f; ssum[r] = 0.f; }

  for (int j0 = 0; j0 < Lp1; j0 += 32) {
    __syncthreads();
    {  // stage K tile (32x64) and V^T tile (64x32), swizzled
      int j = t >> 3, g = t & 7;
      *(s8v*)&Kt[j * 64 + ((g ^ (j & 7)) * 8)] = *(const s8v*)&Kbh[(size_t)(j0 + j) * HD + g * 8];
      int dV = t >> 2, gv = t & 3;
      *(s8v*)&Vt[dV * 32 + ((gv ^ ((dV >> 1) & 3)) * 8)] =
          *(const s8v*)&Vbh[(size_t)dV * NPAD + j0 + gv * 8];
    }
    __syncthreads();

    // S = Q K^T  (two 16x16 j-frags, k = 64 in two steps)
    f4v sf[2];
    { f4v z = {0.f,0.f,0.f,0.f}; sf[0] = z; sf[1] = z; }
    #pragma unroll
    for (int jf = 0; jf < 2; jf++) {
      int j = jf * 16 + lr;                    // B-frag col (l&15)
      #pragma unroll
      for (int kf = 0; kf < 2; kf++) {
        s8v kfr = *(const s8v*)&Kt[j * 64 + (((kf * 4 + lg) ^ (j & 7)) * 8)];
        sf[jf] = __builtin_amdgcn_mfma_f32_16x16x32_bf16(qf[kf], kfr, sf[jf], 0, 0, 0);
      }
    }

    bool ok0 = (j0 + lr)      < Lp1;
    bool ok1 = (j0 + 16 + lr) < Lp1;
    float p0[4], p1[4];
    #pragma unroll
    for (int r = 0; r < 4; r++) {
      float s0 = ok0 ? sf[0][r] : -1e30f;      // select kills any pad NaN
      float s1 = ok1 ? sf[1][r] : -1e30f;
      float tm = fmaxf(s0, s1);
      tm = fmaxf(tm, __shfl_xor(tm, 1)); tm = fmaxf(tm, __shfl_xor(tm, 2));
      tm = fmaxf(tm, __shfl_xor(tm, 4)); tm = fmaxf(tm, __shfl_xor(tm, 8));
      float nm = fmaxf(mrow[r], tm);
      float fs = __expf(mrow[r] - nm);
      mrow[r] = nm;
      float e0 = __expf(s0 - nm), e1 = __expf(s1 - nm);  // masked -> exactly 0
      p0[r] = e0; p1[r] = e1;
      float rs = e0 + e1;
      rs += __shfl_xor(rs, 1); rs += __shfl_xor(rs, 2);
      rs += __shfl_xor(rs, 4); rs += __shfl_xor(rs, 8);
      ssum[r] = ssum[r] * fs + rs;
      o[0][r] *= fs; o[1][r] *= fs; o[2][r] *= fs; o[3][r] *= fs;
    }

    // P (D layout) -> LDS -> A-frag layout
    u16* P = &Pt[w][0];
    #pragma unroll
    for (int r = 0; r < 4; r++) {
      P[(lg * 4 + r) * 40 + lr]      = rne_bf16(p0[r]);
      P[(lg * 4 + r) * 40 + 16 + lr] = rne_bf16(p1[r]);
    }
    asm volatile("s_waitcnt lgkmcnt(0)" ::: "memory");   // wave-local LDS RAW
    s8v pa = *(const s8v*)&P[lr * 40 + lg * 8];
    #pragma unroll
    for (int fd = 0; fd < 4; fd++) {
      int dv = fd * 16 + lr;
      s8v vb = *(const s8v*)&Vt[dv * 32 + ((lg ^ ((dv >> 1) & 3)) * 8)];
      o[fd] = __builtin_amdgcn_mfma_f32_16x16x32_bf16(pa, vb, o[fd], 0, 0, 0);
    }
  }

  float inv[4];
  #pragma unroll
  for (int r = 0; r < 4; r++) inv[r] = 1.0f / ssum[r];
  #pragma unroll
  for (int fd = 0; fd < 4; fd++)
    #pragma unroll
    for (int r = 0; r < 4; r++) {
      int i = q0 + w * 16 + lg * 4 + r;
      if (i < Lp1)
        aout[(size_t)(b * SEQ + i) * DIM + h * HD + fd * 16 + lr] = rne_bf16(o[fd][r] * inv[r]);
    }
}

// ---------------- fill invalid rows with uniform-attention mean(V) -----------
__global__ __launch_bounds__(256) void k_fill(const int* __restrict__ lens,
                                              const float* __restrict__ vmean,
                                              u16* __restrict__ aout) {
  int idx = blockIdx.x * 256 + threadIdx.x;
  if (idx >= MROWS * DIM) return;
  int b = idx / (SEQ * DIM);
  int rem = idx - b * (SEQ * DIM);
  int i = rem / DIM;
  if (i >= lens[b]) {
    int c = rem - i * DIM;
    int h = c >> 6, d = c & 63;
    aout[idx] = rne_bf16(vmean[(b * HEADS + h) * HD + d]);
  }
}

// ---------------- output projection + bias -----------------------------------
__global__ __launch_bounds__(256) void k_gemm_proj(const u16* __restrict__ aout,
                                                   const u16* __restrict__ wprojT,
                                                   const float* __restrict__ bproj,
                                                   float* __restrict__ out) {
  int m0 = blockIdx.x * 128, n0 = blockIdx.y * 128;
  f4v acc[4][4];
  gemm_mainloop(aout, wprojT, MROWS, m0, n0, acc);
  const int t = threadIdx.x;
  const int w = t >> 6, l = t & 63, lg = l >> 4, lr = l & 15;
  const int wr = w >> 1, wc = w & 1;
  #pragma unroll
  for (int fn = 0; fn < 4; fn++) {
    int gc = n0 + wc * 64 + fn * 16 + lr;
    float bias = bproj[gc];
    #pragma unroll
    for (int fm = 0; fm < 4; fm++)
      #pragma unroll
      for (int r = 0; r < 4; r++) {
        int gm = m0 + wr * 64 + fm * 16 + lg * 4 + r;
        if (gm < MROWS) out[(size_t)gm * DIM + gc] = acc[fm][fn][r] + bias;
      }
  }
}

// ---------------- launch ------------------------------------------------------
extern "C" void kernel_launch(void* const* d_in, const int* in_sizes, int n_in,
                              void* d_out, int out_size, void* d_ws, size_t ws_size,
                              hipStream_t stream) {
  const float* x      = (const float*)d_in[0];
  const int*   mask   = (const int*)  d_in[1];
  const float* w_qkv  = (const float*)d_in[2];
  const float* b_qkv  = (const float*)d_in[3];
  const float* w_proj = (const float*)d_in[4];
  const float* b_proj = (const float*)d_in[5];
  float* out = (float*)d_out;

  // workspace layout (bf16 elems); aout aliases xb (xb dead after qkv GEMM)
  u16* xb     = (u16*)d_ws;                          // 8200*768
  u16* wqkvT  = xb    + (size_t)MROWS * DIM;         // 2304*768
  u16* wprojT = wqkvT + (size_t)K3 * DIM;            // 768*768
  u16* Q      = wprojT + (size_t)DIM * DIM;          // 96*1056*64
  u16* Kb     = Q     + (size_t)BHN * NPAD * HD;
  u16* VT     = Kb    + (size_t)BHN * NPAD * HD;
  float* vmean = (float*)(VT + (size_t)BHN * NPAD * HD);
  int* lens    = (int*)(vmean + BHN * HD);
  u16* aout   = xb;                                  // alias: safe, stream-ordered
  // total ~56.3 MB of d_ws

  k_len  <<<dim3(BATCH), dim3(256), 0, stream>>>(mask, lens);
  k_cvt_x<<<dim3((MROWS * DIM / 4 + 255) / 256), dim3(256), 0, stream>>>(x, xb, MROWS * DIM / 4);
  k_wT   <<<dim3(K3 / 32, DIM / 32), dim3(256), 0, stream>>>(w_qkv, wqkvT, DIM, K3);
  k_wT   <<<dim3(DIM / 32, DIM / 32), dim3(256), 0, stream>>>(w_proj, wprojT, DIM, DIM);
  k_zpad <<<dim3((BHN * HD * (NPAD - SEQ) + 255) / 256), dim3(256), 0, stream>>>(VT);
  k_gemm_qkv<<<dim3((MROWS + 127) / 128, K3 / 128), dim3(256), 0, stream>>>(xb, wqkvT, b_qkv, Q, Kb, VT);
  k_vmean<<<dim3(BHN), dim3(256), 0, stream>>>(VT, vmean);
  k_attn <<<dim3((SEQ + 63) / 64, BHN), dim3(256), 0, stream>>>(Q, Kb, VT, lens, aout);
  k_fill <<<dim3((MROWS * DIM + 255) / 256), dim3(256), 0, stream>>>(lens, vmean, aout);
  k_gemm_proj<<<dim3((MROWS + 127) / 128, DIM / 128), dim3(256), 0, stream>>>(aout, wprojT, b_proj, out);
}

// Round 2
// 232.435 us; speedup vs baseline: 1.1011x; 1.1011x over previous
//
#include <hip/hip_runtime.h>
#include <stdint.h>

// Problem constants
#define BATCH   8
#define NMASK_  1024
#define SEQ     1025          // NMASK + 1 (CLS prepended)
#define NPAD    1056          // SEQ padded to multiple of 32
#define DIM     768
#define HEADS   12
#define HD      64
#define BHN     (BATCH*HEADS) // 96
#define MROWS   (BATCH*SEQ)   // 8200
#define K3      (3*DIM)       // 2304

typedef unsigned short u16;
typedef __attribute__((ext_vector_type(8))) short s8v;   // 8 bf16 (A/B frag)
typedef __attribute__((ext_vector_type(4))) float f4v;   // C/D frag
typedef __attribute__((ext_vector_type(4))) unsigned short u16x4;

__device__ __forceinline__ u16 rne_bf16(float f) {
  unsigned u = __float_as_uint(f);
  u += 0x7fffu + ((u >> 16) & 1u);      // round-to-nearest-even
  return (u16)(u >> 16);
}
__device__ __forceinline__ float bf2f(u16 u) {
  return __uint_as_float(((unsigned)u) << 16);
}

// async global->LDS, 16B per lane; LDS dest = wave-uniform base + lane*16
__device__ __forceinline__ void gld16(const u16* g, u16* l) {
  __builtin_amdgcn_global_load_lds(
      (const __attribute__((address_space(1))) void*)g,
      (__attribute__((address_space(3))) void*)l, 16, 0, 0);
}

// ---------------- lengths: Lp1[b] = popcount(mask row) + 1 (CLS) -------------
__global__ __launch_bounds__(256) void k_len(const int* __restrict__ mask,
                                             int* __restrict__ lens) {
  int b = blockIdx.x, t = threadIdx.x;
  int s = 0;
  for (int j = t; j < NMASK_; j += 256) s += (mask[b * NMASK_ + j] != 0) ? 1 : 0;
  __shared__ int red[256];
  red[t] = s; __syncthreads();
  for (int st = 128; st > 0; st >>= 1) { if (t < st) red[t] += red[t + st]; __syncthreads(); }
  if (t == 0) lens[b] = red[0] + 1;
}

// ---------------- x -> bf16 ---------------------------------------------------
__global__ __launch_bounds__(256) void k_cvt_x(const float* __restrict__ x,
                                               u16* __restrict__ xb, int n4) {
  int i = blockIdx.x * 256 + threadIdx.x;
  if (i >= n4) return;
  float4 v = ((const float4*)x)[i];
  u16x4 o;
  o[0] = rne_bf16(v.x); o[1] = rne_bf16(v.y); o[2] = rne_bf16(v.z); o[3] = rne_bf16(v.w);
  *(u16x4*)&xb[i * 4] = o;
}

// ---------------- transpose+convert weights: wT[c][k] = bf16(w[k][c]) --------
__global__ __launch_bounds__(256) void k_wT(const float* __restrict__ w,
                                            u16* __restrict__ wT, int R, int C) {
  __shared__ float tile[32][33];
  int c0 = blockIdx.x * 32, r0 = blockIdx.y * 32;
  int tx = threadIdx.x & 31, ty = threadIdx.x >> 5;   // 32 x 8
  #pragma unroll
  for (int i = 0; i < 32; i += 8) tile[ty + i][tx] = w[(size_t)(r0 + ty + i) * C + c0 + tx];
  __syncthreads();
  #pragma unroll
  for (int i = 0; i < 32; i += 8)
    wT[(size_t)(c0 + ty + i) * R + r0 + tx] = rne_bf16(tile[tx][ty + i]);
}

// ---------------- zero VT pad columns (j in [SEQ, NPAD)) ---------------------
__global__ __launch_bounds__(256) void k_zpad(u16* __restrict__ VT) {
  int idx = blockIdx.x * 256 + threadIdx.x;
  const int PADW = NPAD - SEQ; // 31
  if (idx >= BHN * HD * PADW) return;
  int c = idx % PADW, rd = idx / PADW; // rd = bh*HD + d
  VT[(size_t)rd * NPAD + SEQ + c] = 0;
}

// ---------------- shared 128x128 MFMA mainloop (BK=32, global_load_lds) ------
// m97 structure: linear [128][32] LDS tiles, async 16B/lane staging.
// A: [M][768] bf16 row-major, Bt: [Ncols][768] bf16 (k contiguous)
__device__ __forceinline__ void gemm_mainloop(const u16* __restrict__ A,
                                              const u16* __restrict__ Bt,
                                              int M, int m0, int n0,
                                              f4v acc[4][4]) {
  __shared__ alignas(16) u16 lA[128 * 32];
  __shared__ alignas(16) u16 lB[128 * 32];
  const int t = threadIdx.x;
  const int w = t >> 6, l = t & 63, lg = l >> 4, lr = l & 15;
  const int wr = w >> 1, wc = w & 1;

  // staging map: chunk c = p*256 + t; row = c>>2, seg = c&3; LDS byte = c*16
  int rA0 = m0 + (t >> 2);       if (rA0 >= M) rA0 = M - 1;   // clamp M edge
  int rA1 = m0 + (t >> 2) + 64;  if (rA1 >= M) rA1 = M - 1;
  const u16* sA0 = A  + (size_t)rA0 * DIM + (t & 3) * 8;
  const u16* sA1 = A  + (size_t)rA1 * DIM + (t & 3) * 8;
  const u16* sB0 = Bt + (size_t)(n0 + (t >> 2)) * DIM + (t & 3) * 8;
  const u16* sB1 = Bt + (size_t)(n0 + (t >> 2) + 64) * DIM + (t & 3) * 8;
  u16* dA0 = &lA[w * 512];        // wave-uniform LDS bases
  u16* dA1 = &lA[2048 + w * 512];
  u16* dB0 = &lB[w * 512];
  u16* dB1 = &lB[2048 + w * 512];

  #pragma unroll
  for (int fm = 0; fm < 4; fm++)
    #pragma unroll
    for (int fn = 0; fn < 4; fn++) { f4v z = {0.f, 0.f, 0.f, 0.f}; acc[fm][fn] = z; }

  for (int k0 = 0; k0 < DIM; k0 += 32) {
    __syncthreads();                    // previous compute done before overwrite
    gld16(sA0, dA0); gld16(sA1, dA1);
    gld16(sB0, dB0); gld16(sB1, dB1);
    sA0 += 32; sA1 += 32; sB0 += 32; sB1 += 32;
    __syncthreads();                    // vmcnt(0) drain: tiles visible
    s8v a[4], bb[4];
    #pragma unroll
    for (int fm = 0; fm < 4; fm++) a[fm] = *(const s8v*)&lA[(wr * 64 + fm * 16 + lr) * 32 + lg * 8];
    #pragma unroll
    for (int fn = 0; fn < 4; fn++) bb[fn] = *(const s8v*)&lB[(wc * 64 + fn * 16 + lr) * 32 + lg * 8];
    #pragma unroll
    for (int fm = 0; fm < 4; fm++)
      #pragma unroll
      for (int fn = 0; fn < 4; fn++)
        acc[fm][fn] = __builtin_amdgcn_mfma_f32_16x16x32_bf16(a[fm], bb[fn], acc[fm][fn], 0, 0, 0);
  }
}

// ---------------- QKV GEMM: scatter into Q (x0.125), K, V^T ------------------
__global__ __launch_bounds__(256) void k_gemm_qkv(const u16* __restrict__ xb,
                                                  const u16* __restrict__ wqkvT,
                                                  const float* __restrict__ bqkv,
                                                  u16* __restrict__ Q,
                                                  u16* __restrict__ Kb,
                                                  u16* __restrict__ VT) {
  int m0 = blockIdx.x * 128, n0 = blockIdx.y * 128;
  f4v acc[4][4];
  gemm_mainloop(xb, wqkvT, MROWS, m0, n0, acc);
  const int t = threadIdx.x;
  const int w = t >> 6, l = t & 63, lg = l >> 4, lr = l & 15;
  const int wr = w >> 1, wc = w & 1;
  #pragma unroll
  for (int fn = 0; fn < 4; fn++) {
    int gc = n0 + wc * 64 + fn * 16 + lr;          // 0..2303
    int which = gc / DIM;                          // 0=q 1=k 2=v
    int rem = gc - which * DIM;
    int h = rem >> 6, d = rem & 63;
    float bias = bqkv[gc];
    #pragma unroll
    for (int fm = 0; fm < 4; fm++) {
      #pragma unroll
      for (int r = 0; r < 4; r++) {
        int gm = m0 + wr * 64 + fm * 16 + lg * 4 + r;
        if (gm >= MROWS) continue;
        int b = gm / SEQ, n = gm - b * SEQ;
        int bh = b * HEADS + h;
        float v = acc[fm][fn][r] + bias;
        if (which == 0)      Q [(size_t)(bh * NPAD + n) * HD + d] = rne_bf16(v * 0.125f);
        else if (which == 1) Kb[(size_t)(bh * NPAD + n) * HD + d] = rne_bf16(v);
        else                 VT[(size_t)(bh * HD + d) * NPAD + n] = rne_bf16(v);
      }
    }
  }
}

// ---------------- per-(b,h) mean of V over all SEQ rows ----------------------
__global__ __launch_bounds__(256) void k_vmean(const u16* __restrict__ VT,
                                               float* __restrict__ vmean) {
  int bh = blockIdx.x, t = threadIdx.x;
  int d = t >> 2, part = t & 3;
  const u16* row = VT + (size_t)(bh * HD + d) * NPAD;
  float s = 0.f;
  for (int jc = part * 264; jc < part * 264 + 264; jc += 8) {
    if (jc + 8 <= SEQ) {
      s8v v = *(const s8v*)&row[jc];
      #pragma unroll
      for (int e = 0; e < 8; e++) s += bf2f((u16)v[e]);
    } else {
      for (int e = 0; e < 8; e++) if (jc + e < SEQ) s += bf2f(row[jc + e]);
    }
  }
  __shared__ float red[256];
  red[t] = s; __syncthreads();
  if (part == 0)
    vmean[bh * HD + d] = (red[t] + red[t + 1] + red[t + 2] + red[t + 3]) * (1.0f / (float)SEQ);
}

// ---------------- flash attention over the valid prefix ----------------------
// grid (17, 96); 4 waves x 16 Q-rows. Q pre-scaled by 0.125.
__global__ __launch_bounds__(256) void k_attn(const u16* __restrict__ Q,
                                              const u16* __restrict__ Kb,
                                              const u16* __restrict__ VT,
                                              const int* __restrict__ lens,
                                              u16* __restrict__ aout) {
  int bh = blockIdx.y; int b = bh / HEADS, h = bh - b * HEADS;
  int Lp1 = lens[b];
  int q0 = blockIdx.x * 64;
  if (q0 >= Lp1) return;                      // rows handled by k_fill
  __shared__ alignas(16) u16 Kt[32 * 64];     // [j][d], XOR-swizzled 16B granules
  __shared__ alignas(16) u16 Vt[64 * 32];     // [d][j], XOR-swizzled
  __shared__ alignas(16) u16 Pt[4][16 * 40];  // per-wave P tile, 80B stride
  const int t = threadIdx.x, w = t >> 6, l = t & 63, lg = l >> 4, lr = l & 15;
  const u16* Qbh = Q  + (size_t)bh * NPAD * HD;
  const u16* Kbh = Kb + (size_t)bh * NPAD * HD;
  const u16* Vbh = VT + (size_t)bh * HD * NPAD;

  int qi = q0 + w * 16 + lr;                  // A-frag row (l&15)
  s8v qf[2];
  qf[0] = *(const s8v*)&Qbh[(size_t)qi * HD +      lg * 8];
  qf[1] = *(const s8v*)&Qbh[(size_t)qi * HD + 32 + lg * 8];

  f4v o[4];
  #pragma unroll
  for (int fd = 0; fd < 4; fd++) { f4v z = {0.f, 0.f, 0.f, 0.f}; o[fd] = z; }
  float mrow[4], ssum[4];
  #pragma unroll
  for (int r = 0; r < 4; r++) { mrow[r] = -1e30f; ssum[r] = 0.f; }

  for (int j0 = 0; j0 < Lp1; j0 += 32) {
    __syncthreads();
    {  // stage K tile (32x64) and V^T tile (64x32), swizzled
      int j = t >> 3, g = t & 7;
      *(s8v*)&Kt[j * 64 + ((g ^ (j & 7)) * 8)] = *(const s8v*)&Kbh[(size_t)(j0 + j) * HD + g * 8];
      int dV = t >> 2, gv = t & 3;
      *(s8v*)&Vt[dV * 32 + ((gv ^ ((dV >> 1) & 3)) * 8)] =
          *(const s8v*)&Vbh[(size_t)dV * NPAD + j0 + gv * 8];
    }
    __syncthreads();

    // S = Q K^T  (two 16x16 j-frags, k = 64 in two steps)
    f4v sf[2];
    { f4v z = {0.f,0.f,0.f,0.f}; sf[0] = z; sf[1] = z; }
    #pragma unroll
    for (int jf = 0; jf < 2; jf++) {
      int j = jf * 16 + lr;                    // B-frag col (l&15)
      #pragma unroll
      for (int kf = 0; kf < 2; kf++) {
        s8v kfr = *(const s8v*)&Kt[j * 64 + (((kf * 4 + lg) ^ (j & 7)) * 8)];
        sf[jf] = __builtin_amdgcn_mfma_f32_16x16x32_bf16(qf[kf], kfr, sf[jf], 0, 0, 0);
      }
    }

    bool ok0 = (j0 + lr)      < Lp1;
    bool ok1 = (j0 + 16 + lr) < Lp1;
    float p0[4], p1[4];
    #pragma unroll
    for (int r = 0; r < 4; r++) {
      float s0 = ok0 ? sf[0][r] : -1e30f;      // select kills any pad NaN
      float s1 = ok1 ? sf[1][r] : -1e30f;
      float tm = fmaxf(s0, s1);
      tm = fmaxf(tm, __shfl_xor(tm, 1)); tm = fmaxf(tm, __shfl_xor(tm, 2));
      tm = fmaxf(tm, __shfl_xor(tm, 4)); tm = fmaxf(tm, __shfl_xor(tm, 8));
      float nm = fmaxf(mrow[r], tm);
      float fs = __expf(mrow[r] - nm);
      mrow[r] = nm;
      float e0 = __expf(s0 - nm), e1 = __expf(s1 - nm);  // masked -> exactly 0
      p0[r] = e0; p1[r] = e1;
      float rs = e0 + e1;
      rs += __shfl_xor(rs, 1); rs += __shfl_xor(rs, 2);
      rs += __shfl_xor(rs, 4); rs += __shfl_xor(rs, 8);
      ssum[r] = ssum[r] * fs + rs;
      o[0][r] *= fs; o[1][r] *= fs; o[2][r] *= fs; o[3][r] *= fs;
    }

    // P (D layout) -> LDS -> A-frag layout
    u16* P = &Pt[w][0];
    #pragma unroll
    for (int r = 0; r < 4; r++) {
      P[(lg * 4 + r) * 40 + lr]      = rne_bf16(p0[r]);
      P[(lg * 4 + r) * 40 + 16 + lr] = rne_bf16(p1[r]);
    }
    asm volatile("s_waitcnt lgkmcnt(0)" ::: "memory");   // wave-local LDS RAW
    s8v pa = *(const s8v*)&P[lr * 40 + lg * 8];
    #pragma unroll
    for (int fd = 0; fd < 4; fd++) {
      int dv = fd * 16 + lr;
      s8v vb = *(const s8v*)&Vt[dv * 32 + ((lg ^ ((dv >> 1) & 3)) * 8)];
      o[fd] = __builtin_amdgcn_mfma_f32_16x16x32_bf16(pa, vb, o[fd], 0, 0, 0);
    }
  }

  float inv[4];
  #pragma unroll
  for (int r = 0; r < 4; r++) inv[r] = 1.0f / ssum[r];
  #pragma unroll
  for (int fd = 0; fd < 4; fd++)
    #pragma unroll
    for (int r = 0; r < 4; r++) {
      int i = q0 + w * 16 + lg * 4 + r;
      if (i < Lp1)
        aout[(size_t)(b * SEQ + i) * DIM + h * HD + fd * 16 + lr] = rne_bf16(o[fd][r] * inv[r]);
    }
}

// ---------------- fill invalid rows with uniform-attention mean(V) -----------
__global__ __launch_bounds__(256) void k_fill(const int* __restrict__ lens,
                                              const float* __restrict__ vmean,
                                              u16* __restrict__ aout) {
  int idx = blockIdx.x * 256 + threadIdx.x;
  if (idx >= MROWS * DIM) return;
  int b = idx / (SEQ * DIM);
  int rem = idx - b * (SEQ * DIM);
  int i = rem / DIM;
  if (i >= lens[b]) {
    int c = rem - i * DIM;
    int h = c >> 6, d = c & 63;
    aout[idx] = rne_bf16(vmean[(b * HEADS + h) * HD + d]);
  }
}

// ---------------- output projection + bias -----------------------------------
__global__ __launch_bounds__(256) void k_gemm_proj(const u16* __restrict__ aout,
                                                   const u16* __restrict__ wprojT,
                                                   const float* __restrict__ bproj,
                                                   float* __restrict__ out) {
  int m0 = blockIdx.x * 128, n0 = blockIdx.y * 128;
  f4v acc[4][4];
  gemm_mainloop(aout, wprojT, MROWS, m0, n0, acc);
  const int t = threadIdx.x;
  const int w = t >> 6, l = t & 63, lg = l >> 4, lr = l & 15;
  const int wr = w >> 1, wc = w & 1;
  #pragma unroll
  for (int fn = 0; fn < 4; fn++) {
    int gc = n0 + wc * 64 + fn * 16 + lr;
    float bias = bproj[gc];
    #pragma unroll
    for (int fm = 0; fm < 4; fm++)
      #pragma unroll
      for (int r = 0; r < 4; r++) {
        int gm = m0 + wr * 64 + fm * 16 + lg * 4 + r;
        if (gm < MROWS) out[(size_t)gm * DIM + gc] = acc[fm][fn][r] + bias;
      }
  }
}

// ---------------- launch ------------------------------------------------------
extern "C" void kernel_launch(void* const* d_in, const int* in_sizes, int n_in,
                              void* d_out, int out_size, void* d_ws, size_t ws_size,
                              hipStream_t stream) {
  const float* x      = (const float*)d_in[0];
  const int*   mask   = (const int*)  d_in[1];
  const float* w_qkv  = (const float*)d_in[2];
  const float* b_qkv  = (const float*)d_in[3];
  const float* w_proj = (const float*)d_in[4];
  const float* b_proj = (const float*)d_in[5];
  float* out = (float*)d_out;

  // workspace layout (bf16 elems); aout aliases xb (xb dead after qkv GEMM)
  u16* xb     = (u16*)d_ws;                          // 8200*768
  u16* wqkvT  = xb    + (size_t)MROWS * DIM;         // 2304*768
  u16* wprojT = wqkvT + (size_t)K3 * DIM;            // 768*768
  u16* Q      = wprojT + (size_t)DIM * DIM;          // 96*1056*64
  u16* Kb     = Q     + (size_t)BHN * NPAD * HD;
  u16* VT     = Kb    + (size_t)BHN * NPAD * HD;
  float* vmean = (float*)(VT + (size_t)BHN * NPAD * HD);
  int* lens    = (int*)(vmean + BHN * HD);
  u16* aout   = xb;                                  // alias: safe, stream-ordered
  // total ~56.3 MB of d_ws

  k_len  <<<dim3(BATCH), dim3(256), 0, stream>>>(mask, lens);
  k_cvt_x<<<dim3((MROWS * DIM / 4 + 255) / 256), dim3(256), 0, stream>>>(x, xb, MROWS * DIM / 4);
  k_wT   <<<dim3(K3 / 32, DIM / 32), dim3(256), 0, stream>>>(w_qkv, wqkvT, DIM, K3);
  k_wT   <<<dim3(DIM / 32, DIM / 32), dim3(256), 0, stream>>>(w_proj, wprojT, DIM, DIM);
  k_zpad <<<dim3((BHN * HD * (NPAD - SEQ) + 255) / 256), dim3(256), 0, stream>>>(VT);
  k_gemm_qkv<<<dim3((MROWS + 127) / 128, K3 / 128), dim3(256), 0, stream>>>(xb, wqkvT, b_qkv, Q, Kb, VT);
  k_vmean<<<dim3(BHN), dim3(256), 0, stream>>>(VT, vmean);
  k_attn <<<dim3((SEQ + 63) / 64, BHN), dim3(256), 0, stream>>>(Q, Kb, VT, lens, aout);
  k_fill <<<dim3((MROWS * DIM + 255) / 256), dim3(256), 0, stream>>>(lens, vmean, aout);
  k_gemm_proj<<<dim3((MROWS + 127) / 128, DIM / 128), dim3(256), 0, stream>>>(aout, wprojT, b_proj, out);
}

// Round 3
// 211.028 us; speedup vs baseline: 1.2128x; 1.1014x over previous
//
#include <hip/hip_runtime.h>
#include <stdint.h>

// Problem constants
#define BATCH   8
#define NMASK_  1024
#define SEQ     1025          // NMASK + 1 (CLS prepended)
#define NPAD    1056          // SEQ padded to multiple of 32
#define DIM     768
#define HEADS   12
#define HD      64
#define BHN     (BATCH*HEADS) // 96
#define MROWS   (BATCH*SEQ)   // 8200
#define K3      (3*DIM)       // 2304

typedef unsigned short u16;
typedef __attribute__((ext_vector_type(8))) short s8v;   // 8 bf16 (A/B frag)
typedef __attribute__((ext_vector_type(4))) float f4v;   // C/D frag
typedef __attribute__((ext_vector_type(4))) unsigned short u16x4;

__device__ __forceinline__ u16 rne_bf16(float f) {
  unsigned u = __float_as_uint(f);
  u += 0x7fffu + ((u >> 16) & 1u);      // round-to-nearest-even
  return (u16)(u >> 16);
}
__device__ __forceinline__ float bf2f(u16 u) {
  return __uint_as_float(((unsigned)u) << 16);
}

// async global->LDS, 16B per lane; LDS dest = wave-uniform base + lane*16
__device__ __forceinline__ void gld16(const u16* g, u16* l) {
  __builtin_amdgcn_global_load_lds(
      (const __attribute__((address_space(1))) void*)g,
      (__attribute__((address_space(3))) void*)l, 16, 0, 0);
}

// ---------------- lengths: Lp1[b] = popcount(mask row) + 1 (CLS) -------------
__global__ __launch_bounds__(256) void k_len(const int* __restrict__ mask,
                                             int* __restrict__ lens) {
  int b = blockIdx.x, t = threadIdx.x;
  int s = 0;
  for (int j = t; j < NMASK_; j += 256) s += (mask[b * NMASK_ + j] != 0) ? 1 : 0;
  __shared__ int red[256];
  red[t] = s; __syncthreads();
  for (int st = 128; st > 0; st >>= 1) { if (t < st) red[t] += red[t + st]; __syncthreads(); }
  if (t == 0) lens[b] = red[0] + 1;
}

// ---------------- x -> bf16 ---------------------------------------------------
__global__ __launch_bounds__(256) void k_cvt_x(const float* __restrict__ x,
                                               u16* __restrict__ xb, int n4) {
  int i = blockIdx.x * 256 + threadIdx.x;
  if (i >= n4) return;
  float4 v = ((const float4*)x)[i];
  u16x4 o;
  o[0] = rne_bf16(v.x); o[1] = rne_bf16(v.y); o[2] = rne_bf16(v.z); o[3] = rne_bf16(v.w);
  *(u16x4*)&xb[i * 4] = o;
}

// ---------------- transpose+convert weights: wT[c][k] = bf16(w[k][c]) --------
__global__ __launch_bounds__(256) void k_wT(const float* __restrict__ w,
                                            u16* __restrict__ wT, int R, int C) {
  __shared__ float tile[32][33];
  int c0 = blockIdx.x * 32, r0 = blockIdx.y * 32;
  int tx = threadIdx.x & 31, ty = threadIdx.x >> 5;   // 32 x 8
  #pragma unroll
  for (int i = 0; i < 32; i += 8) tile[ty + i][tx] = w[(size_t)(r0 + ty + i) * C + c0 + tx];
  __syncthreads();
  #pragma unroll
  for (int i = 0; i < 32; i += 8)
    wT[(size_t)(c0 + ty + i) * R + r0 + tx] = rne_bf16(tile[tx][ty + i]);
}

// ---------------- zero VT pad columns (j in [SEQ, NPAD)) ---------------------
__global__ __launch_bounds__(256) void k_zpad(u16* __restrict__ VT) {
  int idx = blockIdx.x * 256 + threadIdx.x;
  const int PADW = NPAD - SEQ; // 31
  if (idx >= BHN * HD * PADW) return;
  int c = idx % PADW, rd = idx / PADW; // rd = bh*HD + d
  VT[(size_t)rd * NPAD + SEQ + c] = 0;
}

// ---------------- shared 128x128 MFMA mainloop (BK=32, dbuf prefetch) --------
// T3-minimum 2-phase: issue next tile's global_load_lds before computing
// current tile; one vmcnt(0)+barrier per K-step (inside __syncthreads).
__device__ __forceinline__ void gemm_mainloop(const u16* __restrict__ A,
                                              const u16* __restrict__ Bt,
                                              int M, int m0, int n0,
                                              f4v acc[4][4]) {
  __shared__ alignas(16) u16 lA[2][128 * 32];   // 16 KiB
  __shared__ alignas(16) u16 lB[2][128 * 32];   // 16 KiB
  const int t = threadIdx.x;
  const int w = t >> 6, l = t & 63, lg = l >> 4, lr = l & 15;
  const int wr = w >> 1, wc = w & 1;

  int rA0 = m0 + (t >> 2);       if (rA0 >= M) rA0 = M - 1;   // clamp M edge
  int rA1 = m0 + (t >> 2) + 64;  if (rA1 >= M) rA1 = M - 1;
  const u16* sA0 = A  + (size_t)rA0 * DIM + (t & 3) * 8;
  const u16* sA1 = A  + (size_t)rA1 * DIM + (t & 3) * 8;
  const u16* sB0 = Bt + (size_t)(n0 + (t >> 2)) * DIM + (t & 3) * 8;
  const u16* sB1 = Bt + (size_t)(n0 + (t >> 2) + 64) * DIM + (t & 3) * 8;
  const int dO0 = w * 512, dO1 = 2048 + w * 512;   // wave-uniform LDS offsets

  #pragma unroll
  for (int fm = 0; fm < 4; fm++)
    #pragma unroll
    for (int fn = 0; fn < 4; fn++) { f4v z = {0.f, 0.f, 0.f, 0.f}; acc[fm][fn] = z; }

  // prologue: stage tile 0 into buffer 0
  gld16(sA0, &lA[0][dO0]); gld16(sA1, &lA[0][dO1]);
  gld16(sB0, &lB[0][dO0]); gld16(sB1, &lB[0][dO1]);
  sA0 += 32; sA1 += 32; sB0 += 32; sB1 += 32;

  int cur = 0;
  for (int k0 = 0; k0 < DIM; k0 += 32) {
    __syncthreads();             // drains vmcnt: buf[cur] ready; buf[cur^1] free
    if (k0 + 32 < DIM) {         // prefetch next K-tile (flies during compute)
      int nx = cur ^ 1;
      gld16(sA0, &lA[nx][dO0]); gld16(sA1, &lA[nx][dO1]);
      gld16(sB0, &lB[nx][dO0]); gld16(sB1, &lB[nx][dO1]);
      sA0 += 32; sA1 += 32; sB0 += 32; sB1 += 32;
    }
    s8v a[4], bb[4];
    #pragma unroll
    for (int fm = 0; fm < 4; fm++) a[fm] = *(const s8v*)&lA[cur][(wr * 64 + fm * 16 + lr) * 32 + lg * 8];
    #pragma unroll
    for (int fn = 0; fn < 4; fn++) bb[fn] = *(const s8v*)&lB[cur][(wc * 64 + fn * 16 + lr) * 32 + lg * 8];
    #pragma unroll
    for (int fm = 0; fm < 4; fm++)
      #pragma unroll
      for (int fn = 0; fn < 4; fn++)
        acc[fm][fn] = __builtin_amdgcn_mfma_f32_16x16x32_bf16(a[fm], bb[fn], acc[fm][fn], 0, 0, 0);
    cur ^= 1;
  }
}

// ---------------- QKV GEMM: scatter into Q (x0.125), K, V^T ------------------
__global__ __launch_bounds__(256) void k_gemm_qkv(const u16* __restrict__ xb,
                                                  const u16* __restrict__ wqkvT,
                                                  const float* __restrict__ bqkv,
                                                  u16* __restrict__ Q,
                                                  u16* __restrict__ Kb,
                                                  u16* __restrict__ VT) {
  int m0 = blockIdx.x * 128, n0 = blockIdx.y * 128;
  f4v acc[4][4];
  gemm_mainloop(xb, wqkvT, MROWS, m0, n0, acc);
  const int t = threadIdx.x;
  const int w = t >> 6, l = t & 63, lg = l >> 4, lr = l & 15;
  const int wr = w >> 1, wc = w & 1;
  #pragma unroll
  for (int fn = 0; fn < 4; fn++) {
    int gc = n0 + wc * 64 + fn * 16 + lr;          // 0..2303
    int which = gc / DIM;                          // 0=q 1=k 2=v
    int rem = gc - which * DIM;
    int h = rem >> 6, d = rem & 63;
    float bias = bqkv[gc];
    #pragma unroll
    for (int fm = 0; fm < 4; fm++) {
      #pragma unroll
      for (int r = 0; r < 4; r++) {
        int gm = m0 + wr * 64 + fm * 16 + lg * 4 + r;
        if (gm >= MROWS) continue;
        int b = gm / SEQ, n = gm - b * SEQ;
        int bh = b * HEADS + h;
        float v = acc[fm][fn][r] + bias;
        if (which == 0)      Q [(size_t)(bh * NPAD + n) * HD + d] = rne_bf16(v * 0.125f);
        else if (which == 1) Kb[(size_t)(bh * NPAD + n) * HD + d] = rne_bf16(v);
        else                 VT[(size_t)(bh * HD + d) * NPAD + n] = rne_bf16(v);
      }
    }
  }
}

// ---------------- per-(b,h) mean of V over all SEQ rows ----------------------
__global__ __launch_bounds__(256) void k_vmean(const u16* __restrict__ VT,
                                               float* __restrict__ vmean) {
  int bh = blockIdx.x, t = threadIdx.x;
  int d = t >> 2, part = t & 3;
  const u16* row = VT + (size_t)(bh * HD + d) * NPAD;
  float s = 0.f;
  for (int jc = part * 264; jc < part * 264 + 264; jc += 8) {
    if (jc + 8 <= SEQ) {
      s8v v = *(const s8v*)&row[jc];
      #pragma unroll
      for (int e = 0; e < 8; e++) s += bf2f((u16)v[e]);
    } else {
      for (int e = 0; e < 8; e++) if (jc + e < SEQ) s += bf2f(row[jc + e]);
    }
  }
  __shared__ float red[256];
  red[t] = s; __syncthreads();
  if (part == 0)
    vmean[bh * HD + d] = (red[t] + red[t + 1] + red[t + 2] + red[t + 3]) * (1.0f / (float)SEQ);
}

// ---------------- flash attention over the valid prefix ----------------------
// grid (17, 96); 4 waves x 16 Q-rows; KVBLK=64; T14 reg-staged issue-early /
// write-late; T13 defer-max; T5 setprio around MFMA clusters.
__global__ __launch_bounds__(256) void k_attn(const u16* __restrict__ Q,
                                              const u16* __restrict__ Kb,
                                              const u16* __restrict__ VT,
                                              const int* __restrict__ lens,
                                              u16* __restrict__ aout) {
  int bh = blockIdx.y; int b = bh / HEADS, h = bh - b * HEADS;
  int Lp1 = lens[b];
  int q0 = blockIdx.x * 64;
  if (q0 >= Lp1) return;                      // rows handled by k_fill
  __shared__ alignas(16) u16 Kt[64 * 64];     // [j][d], XOR-swizzled 16B granules
  __shared__ alignas(16) u16 Vt[64 * 64];     // [d][k], XOR-swizzled
  __shared__ alignas(16) u16 Pt[4][16 * 72];  // per-wave P tile, 144B stride
  const int t = threadIdx.x, w = t >> 6, l = t & 63, lg = l >> 4, lr = l & 15;
  const u16* Qbh = Q  + (size_t)bh * NPAD * HD;
  const u16* Kbh = Kb + (size_t)bh * NPAD * HD;
  const u16* Vbh = VT + (size_t)bh * HD * NPAD;

  int qi = q0 + w * 16 + lr;                  // A-frag row (l&15)
  s8v qf[2];
  qf[0] = *(const s8v*)&Qbh[(size_t)qi * HD +      lg * 8];
  qf[1] = *(const s8v*)&Qbh[(size_t)qi * HD + 32 + lg * 8];

  f4v o[4];
  #pragma unroll
  for (int fd = 0; fd < 4; fd++) { f4v z = {0.f, 0.f, 0.f, 0.f}; o[fd] = z; }
  float mrow[4], ssum[4];
  #pragma unroll
  for (int r = 0; r < 4; r++) { mrow[r] = -1e30f; ssum[r] = 0.f; }

  // T14 staging: per-thread row js (0..63), chunk pair cs/cs+4
  const int js = t >> 2, cs = t & 3;
  const u16* kSrc = Kbh + (size_t)js * HD   + cs * 8;
  const u16* vSrc = Vbh + (size_t)js * NPAD + cs * 8;
  const int kDst0 = js * 64 + ((cs       ^ (js & 7)) * 8);
  const int kDst1 = js * 64 + (((cs + 4) ^ (js & 7)) * 8);
  s8v kr0, kr1, vr0, vr1;
  kr0 = *(const s8v*)(kSrc);        kr1 = *(const s8v*)(kSrc + 32);   // tile 0
  vr0 = *(const s8v*)(vSrc);        vr1 = *(const s8v*)(vSrc + 32);

  for (int j0 = 0; j0 < Lp1; j0 += 64) {
    __syncthreads();                          // Kt/Vt free (prev tile consumed)
    *(s8v*)&Kt[kDst0] = kr0;  *(s8v*)&Kt[kDst1] = kr1;
    *(s8v*)&Vt[kDst0] = vr0;  *(s8v*)&Vt[kDst1] = vr1;
    if (j0 + 64 < Lp1) {                      // issue next loads: fly over compute
      kr0 = *(const s8v*)(kSrc + (size_t)(j0 + 64) * HD);
      kr1 = *(const s8v*)(kSrc + (size_t)(j0 + 64) * HD + 32);
      vr0 = *(const s8v*)(vSrc + (j0 + 64));
      vr1 = *(const s8v*)(vSrc + (j0 + 64) + 32);
    }
    __syncthreads();

    // S = Q K^T  (four 16-col j-frags, k = 64 in two steps)
    f4v sf[4];
    #pragma unroll
    for (int jf = 0; jf < 4; jf++) { f4v z = {0.f,0.f,0.f,0.f}; sf[jf] = z; }
    __builtin_amdgcn_s_setprio(1);
    #pragma unroll
    for (int jf = 0; jf < 4; jf++) {
      int j = jf * 16 + lr;                    // B-frag col (l&15)
      #pragma unroll
      for (int kf = 0; kf < 2; kf++) {
        s8v kfr = *(const s8v*)&Kt[j * 64 + (((kf * 4 + lg) ^ (j & 7)) * 8)];
        sf[jf] = __builtin_amdgcn_mfma_f32_16x16x32_bf16(qf[kf], kfr, sf[jf], 0, 0, 0);
      }
    }
    __builtin_amdgcn_s_setprio(0);

    bool ok[4];
    #pragma unroll
    for (int jf = 0; jf < 4; jf++) ok[jf] = (j0 + jf * 16 + lr) < Lp1;

    float sv[4][4], pmax[4];
    #pragma unroll
    for (int r = 0; r < 4; r++) {
      float s0 = ok[0] ? sf[0][r] : -1e30f;   // select kills any pad NaN
      float s1 = ok[1] ? sf[1][r] : -1e30f;
      float s2 = ok[2] ? sf[2][r] : -1e30f;
      float s3 = ok[3] ? sf[3][r] : -1e30f;
      sv[r][0] = s0; sv[r][1] = s1; sv[r][2] = s2; sv[r][3] = s3;
      float tm = fmaxf(fmaxf(s0, s1), fmaxf(s2, s3));
      tm = fmaxf(tm, __shfl_xor(tm, 1)); tm = fmaxf(tm, __shfl_xor(tm, 2));
      tm = fmaxf(tm, __shfl_xor(tm, 4)); tm = fmaxf(tm, __shfl_xor(tm, 8));
      pmax[r] = tm;
    }
    // T13 defer-max: skip rescale while per-tile max growth <= 8
    bool ng = (pmax[0] <= mrow[0] + 8.f) && (pmax[1] <= mrow[1] + 8.f) &&
              (pmax[2] <= mrow[2] + 8.f) && (pmax[3] <= mrow[3] + 8.f);
    if (!__all(ng)) {
      #pragma unroll
      for (int r = 0; r < 4; r++) {
        float nm = fmaxf(mrow[r], pmax[r]);
        float fs = __expf(mrow[r] - nm);
        mrow[r] = nm;
        ssum[r] *= fs;
        o[0][r] *= fs; o[1][r] *= fs; o[2][r] *= fs; o[3][r] *= fs;
      }
    }
    u16* P = &Pt[w][0];
    #pragma unroll
    for (int r = 0; r < 4; r++) {
      float e0 = __expf(sv[r][0] - mrow[r]);   // masked -> exactly 0
      float e1 = __expf(sv[r][1] - mrow[r]);
      float e2 = __expf(sv[r][2] - mrow[r]);
      float e3 = __expf(sv[r][3] - mrow[r]);
      int prow = (lg * 4 + r) * 72;
      P[prow +      lr] = rne_bf16(e0);
      P[prow + 16 + lr] = rne_bf16(e1);
      P[prow + 32 + lr] = rne_bf16(e2);
      P[prow + 48 + lr] = rne_bf16(e3);
      float rs = (e0 + e1) + (e2 + e3);
      rs += __shfl_xor(rs, 1); rs += __shfl_xor(rs, 2);
      rs += __shfl_xor(rs, 4); rs += __shfl_xor(rs, 8);
      ssum[r] += rs;
    }
    asm volatile("s_waitcnt lgkmcnt(0)" ::: "memory");   // wave-local LDS RAW
    s8v pa[2];
    pa[0] = *(const s8v*)&P[lr * 72 +      lg * 8];
    pa[1] = *(const s8v*)&P[lr * 72 + 32 + lg * 8];
    __builtin_amdgcn_s_setprio(1);
    #pragma unroll
    for (int fd = 0; fd < 4; fd++) {
      int dv = fd * 16 + lr;
      #pragma unroll
      for (int kf = 0; kf < 2; kf++) {
        s8v vb = *(const s8v*)&Vt[dv * 64 + (((kf * 4 + lg) ^ (dv & 7)) * 8)];
        o[fd] = __builtin_amdgcn_mfma_f32_16x16x32_bf16(pa[kf], vb, o[fd], 0, 0, 0);
      }
    }
    __builtin_amdgcn_s_setprio(0);
  }

  float inv[4];
  #pragma unroll
  for (int r = 0; r < 4; r++) inv[r] = 1.0f / ssum[r];
  #pragma unroll
  for (int fd = 0; fd < 4; fd++)
    #pragma unroll
    for (int r = 0; r < 4; r++) {
      int i = q0 + w * 16 + lg * 4 + r;
      if (i < Lp1)
        aout[(size_t)(b * SEQ + i) * DIM + h * HD + fd * 16 + lr] = rne_bf16(o[fd][r] * inv[r]);
    }
}

// ---------------- fill invalid rows with uniform-attention mean(V) -----------
__global__ __launch_bounds__(256) void k_fill(const int* __restrict__ lens,
                                              const float* __restrict__ vmean,
                                              u16* __restrict__ aout) {
  int idx = blockIdx.x * 256 + threadIdx.x;
  if (idx >= MROWS * DIM) return;
  int b = idx / (SEQ * DIM);
  int rem = idx - b * (SEQ * DIM);
  int i = rem / DIM;
  if (i >= lens[b]) {
    int c = rem - i * DIM;
    int h = c >> 6, d = c & 63;
    aout[idx] = rne_bf16(vmean[(b * HEADS + h) * HD + d]);
  }
}

// ---------------- output projection + bias -----------------------------------
__global__ __launch_bounds__(256) void k_gemm_proj(const u16* __restrict__ aout,
                                                   const u16* __restrict__ wprojT,
                                                   const float* __restrict__ bproj,
                                                   float* __restrict__ out) {
  int m0 = blockIdx.x * 128, n0 = blockIdx.y * 128;
  f4v acc[4][4];
  gemm_mainloop(aout, wprojT, MROWS, m0, n0, acc);
  const int t = threadIdx.x;
  const int w = t >> 6, l = t & 63, lg = l >> 4, lr = l & 15;
  const int wr = w >> 1, wc = w & 1;
  #pragma unroll
  for (int fn = 0; fn < 4; fn++) {
    int gc = n0 + wc * 64 + fn * 16 + lr;
    float bias = bproj[gc];
    #pragma unroll
    for (int fm = 0; fm < 4; fm++)
      #pragma unroll
      for (int r = 0; r < 4; r++) {
        int gm = m0 + wr * 64 + fm * 16 + lg * 4 + r;
        if (gm < MROWS) out[(size_t)gm * DIM + gc] = acc[fm][fn][r] + bias;
      }
  }
}

// ---------------- launch ------------------------------------------------------
extern "C" void kernel_launch(void* const* d_in, const int* in_sizes, int n_in,
                              void* d_out, int out_size, void* d_ws, size_t ws_size,
                              hipStream_t stream) {
  const float* x      = (const float*)d_in[0];
  const int*   mask   = (const int*)  d_in[1];
  const float* w_qkv  = (const float*)d_in[2];
  const float* b_qkv  = (const float*)d_in[3];
  const float* w_proj = (const float*)d_in[4];
  const float* b_proj = (const float*)d_in[5];
  float* out = (float*)d_out;

  // workspace layout (bf16 elems); aout aliases xb (xb dead after qkv GEMM)
  u16* xb     = (u16*)d_ws;                          // 8200*768
  u16* wqkvT  = xb    + (size_t)MROWS * DIM;         // 2304*768
  u16* wprojT = wqkvT + (size_t)K3 * DIM;            // 768*768
  u16* Q      = wprojT + (size_t)DIM * DIM;          // 96*1056*64
  u16* Kb     = Q     + (size_t)BHN * NPAD * HD;
  u16* VT     = Kb    + (size_t)BHN * NPAD * HD;
  float* vmean = (float*)(VT + (size_t)BHN * NPAD * HD);
  int* lens    = (int*)(vmean + BHN * HD);
  u16* aout   = xb;                                  // alias: safe, stream-ordered
  // total ~56.3 MB of d_ws

  k_len  <<<dim3(BATCH), dim3(256), 0, stream>>>(mask, lens);
  k_cvt_x<<<dim3((MROWS * DIM / 4 + 255) / 256), dim3(256), 0, stream>>>(x, xb, MROWS * DIM / 4);
  k_wT   <<<dim3(K3 / 32, DIM / 32), dim3(256), 0, stream>>>(w_qkv, wqkvT, DIM, K3);
  k_wT   <<<dim3(DIM / 32, DIM / 32), dim3(256), 0, stream>>>(w_proj, wprojT, DIM, DIM);
  k_zpad <<<dim3((BHN * HD * (NPAD - SEQ) + 255) / 256), dim3(256), 0, stream>>>(VT);
  k_gemm_qkv<<<dim3((MROWS + 127) / 128, K3 / 128), dim3(256), 0, stream>>>(xb, wqkvT, b_qkv, Q, Kb, VT);
  k_vmean<<<dim3(BHN), dim3(256), 0, stream>>>(VT, vmean);
  k_attn <<<dim3((SEQ + 63) / 64, BHN), dim3(256), 0, stream>>>(Q, Kb, VT, lens, aout);
  k_fill <<<dim3((MROWS * DIM + 255) / 256), dim3(256), 0, stream>>>(lens, vmean, aout);
  k_gemm_proj<<<dim3((MROWS + 127) / 128, DIM / 128), dim3(256), 0, stream>>>(aout, wprojT, b_proj, out);
}